// Round 7
// baseline (157.368 us; speedup 1.0000x reference)
//
#include <hip/hip_runtime.h>
#include <hip/hip_fp8.h>

#define P 196
#define NN 32
#define MARGIN 0.5f
#define NCH 12            // K-chunks of 64 fp8 elements
#define APIECES 896       // A: 224 rows * 4 pieces (16 B) per chunk
#define BPIECES 448       // B q-half: 112 rows * 4 pieces
#define TPB (APIECES + BPIECES)        // 1344 pieces per buffer
#define BUFB (TPB * 16)                // 21504 bytes per buffer
#define CHB (APIECES * 16)             // 14336 bytes per image-chunk

typedef long  longx2  __attribute__((ext_vector_type(2)));   // 16 B = 2 fp8 half-frags
typedef float floatx4 __attribute__((ext_vector_type(4)));   // 16x16 MFMA C/D frag

typedef __attribute__((address_space(1))) const unsigned char g_u8;
typedef __attribute__((address_space(3))) unsigned char l_u8;

// Workspace Y layout (fp8 e4m3, chunk-major, swizzled) — HW-verified R8:
//   chunk c covers k = c*64..c*64+63. Piece(img,c,r,kg') = 16 B at
//   (img*12 + c)*14336 + (r*4 + kg')*16, kg' = kg ^ ((r>>1)&3).
//   Piece bytes 0-7 = k_local [kg*8,+8) (s=0); bytes 8-15 = [32+kg*8,+8) (s=1)
//   -> one ds_read_b128 feeds TWO 16x16x32 fp8 MFMAs.

// ---------------------------------------------------------------------------
// Kernel 1 (unchanged, HW-verified): 8 waves/block, one row per wave.
// ---------------------------------------------------------------------------
__global__ __launch_bounds__(512) void norm_kernel(const float* __restrict__ nrm,
                                                   const float* __restrict__ dft,
                                                   unsigned char* __restrict__ Y,
                                                   float* __restrict__ out) {
    if (blockIdx.x == 0 && threadIdx.x == 0) out[0] = 0.0f;
    __shared__ uint2 rowbuf[8][100];             // 96 groups of 8 fp8 per row

    int img  = blockIdx.x / 28;
    int rg   = blockIdx.x % 28;
    int wave = threadIdx.x >> 6;
    int lane = threadIdx.x & 63;
    int p = rg * 8 + wave;

    if (p < P) {
        const float* src = (img < NN) ? nrm + ((size_t)img * P + p) * 768
                                      : dft + ((size_t)(img - NN) * P + p) * 768;
        float4 a0 = *(const float4*)(src + lane * 8);
        float4 a1 = *(const float4*)(src + lane * 8 + 4);
        float4 b0 = {0,0,0,0}, b1 = {0,0,0,0};
        float ss = a0.x*a0.x + a0.y*a0.y + a0.z*a0.z + a0.w*a0.w
                 + a1.x*a1.x + a1.y*a1.y + a1.z*a1.z + a1.w*a1.w;
        if (lane < 32) {
            b0 = *(const float4*)(src + 512 + lane * 8);
            b1 = *(const float4*)(src + 512 + lane * 8 + 4);
            ss += b0.x*b0.x + b0.y*b0.y + b0.z*b0.z + b0.w*b0.w
                + b1.x*b1.x + b1.y*b1.y + b1.z*b1.z + b1.w*b1.w;
        }
        #pragma unroll
        for (int o = 32; o > 0; o >>= 1) ss += __shfl_xor(ss, o);
        float inv = 1.0f / (sqrtf(ss) + 1e-8f);

        auto q8 = [&](float f) -> unsigned {     // fp32 -> OCP e4m3 byte
            return (unsigned)__hip_fp8_e4m3(f).__x;
        };
        auto pack8 = [&](float4 x0, float4 x1) {
            uint2 g;
            g.x = q8(x0.x*inv) | (q8(x0.y*inv) << 8) |
                  (q8(x0.z*inv) << 16) | (q8(x0.w*inv) << 24);
            g.y = q8(x1.x*inv) | (q8(x1.y*inv) << 8) |
                  (q8(x1.z*inv) << 16) | (q8(x1.w*inv) << 24);
            return g;
        };
        rowbuf[wave][lane] = pack8(a0, a1);                     // groups 0..63
        if (lane < 32) rowbuf[wave][64 + lane] = pack8(b0, b1); // groups 64..95
    }
    __syncthreads();

    int idx = threadIdx.x;
    if (idx < 384) {
        int c = idx >> 5, r = (idx >> 2) & 7, kgp = idx & 3;
        int pr = rg * 8 + r;
        if (pr < P) {
            int kg = kgp ^ ((pr >> 1) & 3);
            uint2 lo = rowbuf[r][c * 8 + kg];        // s=0 half
            uint2 hi = rowbuf[r][c * 8 + 4 + kg];    // s=1 half
            uint4 o; o.x = lo.x; o.y = lo.y; o.z = hi.x; o.w = hi.y;
            *(uint4*)(Y + (size_t)(img * NCH + c) * CHB + (pr * 4 + kgp) * 16) = o;
        }
    }
}

// ---------------------------------------------------------------------------
// Pair ordering table (compile-time): macro-tiled for L2 locality (R10,
// verified: FETCH 33 -> 25.7 MB). v[b] = ia | (ja<<8), ja global index.
// ---------------------------------------------------------------------------
struct PairTab { unsigned short v[1520]; };
static constexpr PairTab mk_tab() {
    PairTab t{};
    int n = 0;
    for (int gi = 0; gi < 4; ++gi)                  // nn: 496 pairs, i<j
        for (int gj = gi; gj < 4; ++gj)
            for (int i = gi*8; i < gi*8 + 8; ++i) {
                int j0 = (gi == gj) ? i + 1 : gj*8;
                for (int j = j0; j < gj*8 + 8; ++j)
                    t.v[n++] = (unsigned short)(i | (j << 8));
            }
    for (int gi = 0; gi < 4; ++gi)                  // nd: 1024 pairs
        for (int gd = 0; gd < 4; ++gd)
            for (int i = gi*8; i < gi*8 + 8; ++i)
                for (int d = gd*8; d < gd*8 + 8; ++d)
                    t.v[n++] = (unsigned short)(i | ((32 + d) << 8));
    return t;
}
__constant__ PairTab PTAB = mk_tab();

// ---------------------------------------------------------------------------
// Kernel 2 (R15): register-level FRAG DOUBLE-BANKING (T3 intra-phase
// pipeline) + dead-tile skip for qh=1.
//   R13 (depth-2 vmcnt) and R14 (-21% reads) both ~nil => the 35% bubble is
//   the per-phase serial chain barrier -> ds_read -> lgkm(~150cyc) -> MFMA.
//   Now phase t: {read chunk-t frags -> bank X} issued first, then the MFMA
//   burst for chunk t-1 runs from bank Y (loaded last phase, already
//   waited). Read latency hides under ~390 cyc of MFMAs; MFMAs start at
//   barrier-exit. Phase-end lgkmcnt(0) is post-burst (off critical path)
//   and preserves the cross-wave buffer-reuse proof: reads of buf[t%3]
//   complete before B_{t+1}, restage of that buffer happens after B_{t+1}.
//   Rects re-balanced to cap tiles<=12/wave (acc<=48 AGPR) so the doubled
//   frag banks fit: arch ~60-70 + 48 agpr < 128 cap of (512,4).
//   qh=1 skip: B-tile col 6 = q 208..223, ALL pad -> skip read+13 tile-MFMAs
//   (one uniform branch; -7% total MFMA). Epilogue mask already drops q>=196.
// Staging (21 DMAs, i=W+8u), swizzle, 3-buffer depth-2 counted vmcnt, and
// epilogue are carried unchanged from R13/R14 (proven correct, conflicts 0).
// ---------------------------------------------------------------------------
__device__ constexpr int WAS[8] = {0, 0, 6, 6,  0, 4, 8, 12};   // A start
__device__ constexpr int WAC[8] = {6, 6, 6, 6,  4, 4, 4, 1};    // A count
__device__ constexpr int WBS[8] = {0, 2, 0, 2,  4, 4, 4, 0};    // B start
__device__ constexpr int WBC[8] = {2, 2, 2, 2,  3, 3, 3, 7};    // B count
// coverage: B0-1: w0(A0-5)+w2(A6-11)+w7(A12); B2-3: w1+w3+w7;
//           B4-6: w4(A0-3)+w5(A4-7)+w6(A8-11)+w7(A12).  Sum = 91 tiles.

template<int W>
__device__ void wave_worker(uint4* tiles, const unsigned char* gA,
                            const unsigned char* gB, int lane, bool skip6) {
    constexpr int AS = WAS[W], AC = WAC[W], BS = WBS[W], BC = WBC[W];
    constexpr int BCM = (BS + BC - 1 == 6) ? BC - 1 : BC;  // cols always computed
    constexpr int VM = (W < 5) ? 3 : 2;   // own DMAs per chunk (i = W+8u < 21)

    int r16  = lane & 15;
    int quad = lane >> 4;                 // 0..3 : k-group of 8
    int sw   = quad ^ ((r16 >> 1) & 3);   // XOR swizzle (verified conflict-free)
    const char* abp = (const char*)tiles + (r16 * 4 + sw) * 16;
    const char* bbp = (const char*)tiles + APIECES * 16 + (r16 * 4 + sw) * 16;
    l_u8* lds0 = (l_u8*)tiles;

    floatx4 acc[AC][BC];
    #pragma unroll
    for (int a = 0; a < AC; ++a)
        #pragma unroll
        for (int b = 0; b < BC; ++b)
            acc[a][b] = (floatx4){0.f, 0.f, 0.f, 0.f};

    longx2 fa0[AC], fb0[BC], fa1[AC], fb1[BC];   // two frag banks

    // 21 DMA instrs/chunk over 8 waves: wave W issues i = W, W+8, W+16 (<21)
    auto stage = [&](const unsigned char* ga, const unsigned char* gb, l_u8* ldsb) {
        #pragma unroll
        for (int u = 0; u < 3; ++u) {
            if (W + 8 * u < 21) {
                int i = W + 8 * u;
                const unsigned char* g = (i < 14) ? ga + (i * 64 + lane) * 16
                                                  : gb + ((i - 14) * 64 + lane) * 16;
                __builtin_amdgcn_global_load_lds((const g_u8*)g, ldsb + i * 1024, 16, 0, 0);
            }
        }
    };

    auto readf = [&](int cc, longx2* af, longx2* bf) {
        const char* ab = abp + cc * BUFB;
        const char* bb = bbp + cc * BUFB;
        #pragma unroll
        for (int a = 0; a < AC; ++a)
            af[a] = *(const longx2*)(ab + (AS + a) * 1024);
        #pragma unroll
        for (int b = 0; b < BCM; ++b)
            bf[b] = *(const longx2*)(bb + (BS + b) * 1024);
        if (BCM != BC && !skip6)                  // col-6 tile (pad when qh=1)
            bf[BC - 1] = *(const longx2*)(bb + 6 * 1024);
    };

    auto burst = [&](const longx2* af, const longx2* bf) {
        __builtin_amdgcn_s_setprio(1);
        #pragma unroll
        for (int s = 0; s < 2; ++s)
            #pragma unroll
            for (int a = 0; a < AC; ++a)
                #pragma unroll
                for (int b = 0; b < BCM; ++b)
                    acc[a][b] = __builtin_amdgcn_mfma_f32_16x16x32_fp8_fp8(
                        af[a][s], bf[b][s], acc[a][b], 0, 0, 0);
        if (BCM != BC && !skip6) {
            #pragma unroll
            for (int s = 0; s < 2; ++s)
                #pragma unroll
                for (int a = 0; a < AC; ++a)
                    acc[a][BC - 1] = __builtin_amdgcn_mfma_f32_16x16x32_fp8_fp8(
                        af[a][s], bf[BC - 1][s], acc[a][BC - 1], 0, 0, 0);
        }
        __builtin_amdgcn_s_setprio(0);
    };

    stage(gA, gB, lds0);                 gA += CHB; gB += CHB;   // c0 -> buf0
    stage(gA, gB, lds0 + BUFB);          gA += CHB; gB += CHB;   // c1 -> buf1

    // phase 0: chunk-0 frags -> bank0; stage chunk 2; no MFMA yet
    __builtin_amdgcn_s_waitcnt(0xF70 | VM);      // own(c0) done, c1 in flight
    __builtin_amdgcn_s_barrier();
    __builtin_amdgcn_sched_barrier(0);
    readf(0, fa0, fb0);
    stage(gA, gB, lds0 + 2 * BUFB);      gA += CHB; gB += CHB;   // c2 -> buf2
    __builtin_amdgcn_s_waitcnt(0xC07F);          // lgkmcnt(0): bank0 ready

    #pragma unroll
    for (int tt = 0; tt < 5; ++tt) {
        {   // odd phase t = 2tt+1 (1,3,5,7,9): read c_t -> bank1, MFMA c_{t-1}
            int t = 2 * tt + 1;                  // folds (tt unrolled)
            __builtin_amdgcn_s_waitcnt(0xF70 | VM);
            __builtin_amdgcn_s_barrier();
            __builtin_amdgcn_sched_barrier(0);
            readf(t % 3, fa1, fb1);
            stage(gA, gB, lds0 + ((t + 2) % 3) * BUFB);  gA += CHB; gB += CHB;
            burst(fa0, fb0);
            __builtin_amdgcn_s_waitcnt(0xC07F);  // bank1 ready; gates B_{t+1}
        }
        {   // even phase t = 2tt+2 (2,4,6,8,10): read c_t -> bank0, MFMA c_{t-1}
            int t = 2 * tt + 2;
            __builtin_amdgcn_s_waitcnt(0xF70 | VM);
            __builtin_amdgcn_s_barrier();
            __builtin_amdgcn_sched_barrier(0);
            readf(t % 3, fa0, fb0);
            if (t <= 9) {                        // t=10 has nothing left to stage
                stage(gA, gB, lds0 + ((t + 2) % 3) * BUFB);  gA += CHB; gB += CHB;
            }
            burst(fa1, fb1);
            __builtin_amdgcn_s_waitcnt(0xC07F);
        }
    }
    // phase 11: read c11 -> bank1, MFMA c10 (bank0); then finish c11
    __builtin_amdgcn_s_waitcnt(0xF70);           // vmcnt(0): last DMAs
    __builtin_amdgcn_s_barrier();
    __builtin_amdgcn_sched_barrier(0);
    readf(2, fa1, fb1);
    burst(fa0, fb0);
    __builtin_amdgcn_s_waitcnt(0xC07F);
    burst(fa1, fb1);                             // chunk 11

    __syncthreads();                 // all waves' tile reads done; alias LDS
    float* colmaxrow = (float*)tiles + W * 112;

    // C/D: col q = lane&15, row p = (AS+a)*16 + quad*4 + r
    #pragma unroll
    for (int b = 0; b < BC; ++b) {
        float m = -3.0e38f;
        #pragma unroll
        for (int a = 0; a < AC; ++a) {
            int pbase = (AS + a) * 16 + quad * 4;
            #pragma unroll
            for (int r = 0; r < 4; ++r)
                if (pbase + r < P) m = fmaxf(m, acc[a][b][r]);
        }
        m = fmaxf(m, __shfl_xor(m, 16));
        m = fmaxf(m, __shfl_xor(m, 32));
        if (quad == 0) colmaxrow[(BS + b) * 16 + r16] = m;
    }
    // non-owned columns of this wave's row: neutral element (final reduce
    // maxes over all 8 rows; stale LDS there would alias tile data)
    #pragma unroll
    for (int t = 0; t < 7; ++t)
        if (t < BS || t >= BS + BC)
            if (quad == 0) colmaxrow[t * 16 + r16] = -3.0e38f;
}

__global__ __launch_bounds__(512, 4) void pair_kernel(const unsigned char* __restrict__ Y,
                                                      float* __restrict__ out) {
    __shared__ uint4 tiles[3 * TPB];   // 64512 B (colmax aliased in epilogue)
    __shared__ float redp[8];

    int bx = blockIdx.x;
    int l  = (bx & 7) * 380 + (bx >> 3);   // XCD k owns logical [380k, 380k+380)
    int b  = l >> 1;                 // pair index (macro-tiled order)
    int qh = l & 1;                  // q-half
    unsigned short pk = PTAB.v[b];
    int ia = pk & 255;
    int ja = pk >> 8;
    bool is_nn = b < 496;
    bool skip6 = (qh == 1);          // B-tile col 6 = q 208..223: all pad

    int tid  = threadIdx.x;
    int lane = tid & 63;
    int wave = tid >> 6;             // 0..7

    const unsigned char* gA = Y + (size_t)ia * (NCH * CHB);
    const unsigned char* gB = Y + (size_t)ja * (NCH * CHB) + qh * (BPIECES * 16);

    switch (wave) {
        case 0: wave_worker<0>(tiles, gA, gB, lane, skip6); break;
        case 1: wave_worker<1>(tiles, gA, gB, lane, skip6); break;
        case 2: wave_worker<2>(tiles, gA, gB, lane, skip6); break;
        case 3: wave_worker<3>(tiles, gA, gB, lane, skip6); break;
        case 4: wave_worker<4>(tiles, gA, gB, lane, skip6); break;
        case 5: wave_worker<5>(tiles, gA, gB, lane, skip6); break;
        case 6: wave_worker<6>(tiles, gA, gB, lane, skip6); break;
        default: wave_worker<7>(tiles, gA, gB, lane, skip6); break;
    }

    __syncthreads();                 // all colmax rows written
    float* colmax = (float*)tiles;   // [8][112]

    float contrib = 0.f;
    if (tid < 112 && qh * 112 + tid < P) {       // q >= 196 are pad cols
        float cm = colmax[tid];
        #pragma unroll
        for (int w = 1; w < 8; ++w) cm = fmaxf(cm, colmax[w * 112 + tid]);
        contrib = is_nn ? (1.0f - cm) * (1.0f / (496.0f * 196.0f))
                        : fmaxf(cm - MARGIN, 0.0f) * (1.0f / (1024.0f * 196.0f));
    }
    #pragma unroll
    for (int o = 32; o > 0; o >>= 1) contrib += __shfl_down(contrib, o);
    if (lane == 0) redp[wave] = contrib;
    __syncthreads();
    if (tid == 0) {
        float s = redp[0] + redp[1] + redp[2] + redp[3]
                + redp[4] + redp[5] + redp[6] + redp[7];
        atomicAdd(out, s);
    }
}

// ---------------------------------------------------------------------------
extern "C" void kernel_launch(void* const* d_in, const int* in_sizes, int n_in,
                              void* d_out, int out_size, void* d_ws, size_t ws_size,
                              hipStream_t stream) {
    const float* nrm = (const float*)d_in[0];   // [32,196,768] fp32
    const float* dft = (const float*)d_in[1];   // [32,196,768] fp32
    float* out = (float*)d_out;                 // scalar fp32
    unsigned char* Y = (unsigned char*)d_ws;    // fp8 e4m3, 10.5 MB

    norm_kernel<<<64 * 28, 512, 0, stream>>>(nrm, dft, Y, out);
    pair_kernel<<<2 * (496 + 1024), 512, 0, stream>>>(Y, out);
}

// Round 8
// 135.963 us; speedup vs baseline: 1.1574x; 1.1574x over previous
//
#include <hip/hip_runtime.h>
#include <hip/hip_fp8.h>

#define P 196
#define NN 32
#define MARGIN 0.5f
#define NCH 12            // K-chunks of 64 int8 elements
#define APIECES 896       // A: 224 rows * 4 pieces (16 B) per chunk
#define BPIECES 448       // B q-half: 112 rows * 4 pieces
#define TPB (APIECES + BPIECES)        // 1344 pieces per buffer
#define BUFB (TPB * 16)                // 21504 bytes per buffer
#define CHB (APIECES * 16)             // 14336 bytes per image-chunk

#define QS 400.0f                      // int8 quant scale: x_int = round(x*QS)
#define INV_QS2 (1.0f / (QS * QS))     // sim = int_dot * INV_QS2

typedef int   intx4   __attribute__((ext_vector_type(4)));   // 16 B = one K=64 i8 frag
typedef float floatx4 __attribute__((ext_vector_type(4)));

typedef __attribute__((address_space(1))) const unsigned char g_u8;
typedef __attribute__((address_space(3))) unsigned char l_u8;

// Workspace Y layout (int8 symmetric-quant, chunk-major, swizzled). Geometry
// is IDENTICAL to the HW-verified fp8 layout (R8): chunk c covers k =
// c*64..c*64+63; piece(img,c,r,kg') = 16 B at (img*12+c)*14336+(r*4+kg')*16,
// kg' = kg ^ ((r>>1)&3); piece bytes 0-7 = k[kg*8,+8), 8-15 = k[32+kg*8,+8).
// R16: values are int8 = round(x_normalized * QS), clamp +-127. One piece =
// one 4-VGPR operand of mfma_i32_16x16x64_i8 (K=64 -> ONE mfma per tile-chunk,
// ~2x OP rate vs fp8). Correctness of the k-order: A and B pieces share the
// same (lane,byte)->k permutation, and the dot is permutation-invariant —
// same argument validated by R11's K=128 MX run (absmax 0).

// ---------------------------------------------------------------------------
// Kernel 1: normalize + int8 quantize (was fp8). Structure unchanged.
// Pad rows (p>=196) keep ws poison (finite i8, masked in consumers).
// ---------------------------------------------------------------------------
__global__ __launch_bounds__(512) void norm_kernel(const float* __restrict__ nrm,
                                                   const float* __restrict__ dft,
                                                   unsigned char* __restrict__ Y,
                                                   float* __restrict__ out) {
    if (blockIdx.x == 0 && threadIdx.x == 0) out[0] = 0.0f;
    __shared__ uint2 rowbuf[8][100];             // 96 groups of 8 bytes per row

    int img  = blockIdx.x / 28;
    int rg   = blockIdx.x % 28;
    int wave = threadIdx.x >> 6;
    int lane = threadIdx.x & 63;
    int p = rg * 8 + wave;

    if (p < P) {
        const float* src = (img < NN) ? nrm + ((size_t)img * P + p) * 768
                                      : dft + ((size_t)(img - NN) * P + p) * 768;
        float4 a0 = *(const float4*)(src + lane * 8);
        float4 a1 = *(const float4*)(src + lane * 8 + 4);
        float4 b0 = {0,0,0,0}, b1 = {0,0,0,0};
        float ss = a0.x*a0.x + a0.y*a0.y + a0.z*a0.z + a0.w*a0.w
                 + a1.x*a1.x + a1.y*a1.y + a1.z*a1.z + a1.w*a1.w;
        if (lane < 32) {
            b0 = *(const float4*)(src + 512 + lane * 8);
            b1 = *(const float4*)(src + 512 + lane * 8 + 4);
            ss += b0.x*b0.x + b0.y*b0.y + b0.z*b0.z + b0.w*b0.w
                + b1.x*b1.x + b1.y*b1.y + b1.z*b1.z + b1.w*b1.w;
        }
        #pragma unroll
        for (int o = 32; o > 0; o >>= 1) ss += __shfl_xor(ss, o);
        float qsc = QS / (sqrtf(ss) + 1e-8f);    // normalize * quant scale

        auto qi = [&](float f) -> unsigned {     // fp32 -> clamped int8 byte
            float v = f * qsc;
            v = fminf(fmaxf(v, -127.0f), 127.0f);
            return (unsigned)((int)rintf(v) & 255);
        };
        auto pack8 = [&](float4 x0, float4 x1) {
            uint2 g;
            g.x = qi(x0.x) | (qi(x0.y) << 8) | (qi(x0.z) << 16) | (qi(x0.w) << 24);
            g.y = qi(x1.x) | (qi(x1.y) << 8) | (qi(x1.z) << 16) | (qi(x1.w) << 24);
            return g;
        };
        rowbuf[wave][lane] = pack8(a0, a1);                     // groups 0..63
        if (lane < 32) rowbuf[wave][64 + lane] = pack8(b0, b1); // groups 64..95
    }
    __syncthreads();

    int idx = threadIdx.x;
    if (idx < 384) {
        int c = idx >> 5, r = (idx >> 2) & 7, kgp = idx & 3;
        int pr = rg * 8 + r;
        if (pr < P) {
            int kg = kgp ^ ((pr >> 1) & 3);
            uint2 lo = rowbuf[r][c * 8 + kg];        // k-low half
            uint2 hi = rowbuf[r][c * 8 + 4 + kg];    // k-high half
            uint4 o; o.x = lo.x; o.y = lo.y; o.z = hi.x; o.w = hi.y;
            *(uint4*)(Y + (size_t)(img * NCH + c) * CHB + (pr * 4 + kgp) * 16) = o;
        }
    }
}

// ---------------------------------------------------------------------------
// Pair ordering table (compile-time): macro-tiled for L2 locality (R10,
// verified: FETCH 33 -> 25.7 MB). v[b] = ia | (ja<<8), ja global index.
// ---------------------------------------------------------------------------
struct PairTab { unsigned short v[1520]; };
static constexpr PairTab mk_tab() {
    PairTab t{};
    int n = 0;
    for (int gi = 0; gi < 4; ++gi)                  // nn: 496 pairs, i<j
        for (int gj = gi; gj < 4; ++gj)
            for (int i = gi*8; i < gi*8 + 8; ++i) {
                int j0 = (gi == gj) ? i + 1 : gj*8;
                for (int j = j0; j < gj*8 + 8; ++j)
                    t.v[n++] = (unsigned short)(i | (j << 8));
            }
    for (int gi = 0; gi < 4; ++gi)                  // nd: 1024 pairs
        for (int gd = 0; gd < 4; ++gd)
            for (int i = gi*8; i < gi*8 + 8; ++i)
                for (int d = gd*8; d < gd*8 + 8; ++d)
                    t.v[n++] = (unsigned short)(i | ((32 + d) << 8));
    return t;
}
__constant__ PairTab PTAB = mk_tab();

// ---------------------------------------------------------------------------
// Kernel 2 (R16): R14's proven skeleton (rect wave->tile split, 3-buffer
// depth-2 counted vmcnt, swizzle, epilogue) with fp8 MFMA pairs swapped for
// ONE mfma_i32_16x16x64_i8 per tile-chunk:
//   * K=64/instr at ~2x OP rate (3944 TOPS, m16) -> MFMA pipe 52 -> ~27 us.
//   * Operand = 4 VGPRs = exactly one 16-B piece; register footprint
//     IDENTICAL to R14 (no double-banking — R15's spill lesson).
//   * Accumulate exact i32; max in int (monotone); one float convert
//     (* INV_QS2) per column at the end.
// R15's skip6 and frag banks are NOT carried (single-variable discipline).
// ---------------------------------------------------------------------------
__device__ constexpr int WAS[8] = {0, 0, 7, 7,  4, 7, 10, 0};   // A start
__device__ constexpr int WAC[8] = {7, 7, 6, 6,  3, 3,  3, 4};   // A count
__device__ constexpr int WBS[8] = {0, 2, 0, 2,  4, 4,  4, 4};   // B start
__device__ constexpr int WBC[8] = {2, 2, 2, 2,  3, 3,  3, 3};   // B count

template<int W>
__device__ void wave_worker(uint4* tiles, const unsigned char* gA,
                            const unsigned char* gB, int lane) {
    constexpr int AS = WAS[W], AC = WAC[W], BS = WBS[W], BC = WBC[W];
    constexpr int VM = (W < 5) ? 3 : 2;   // own DMAs per chunk (i = W+8u < 21)

    int r16  = lane & 15;
    int quad = lane >> 4;                 // 0..3 : k-group of 8
    int sw   = quad ^ ((r16 >> 1) & 3);   // XOR swizzle (verified conflict-free)
    const char* abp = (const char*)tiles + (r16 * 4 + sw) * 16;
    const char* bbp = (const char*)tiles + APIECES * 16 + (r16 * 4 + sw) * 16;
    l_u8* lds0 = (l_u8*)tiles;

    intx4 acc[AC][BC];
    #pragma unroll
    for (int a = 0; a < AC; ++a)
        #pragma unroll
        for (int b = 0; b < BC; ++b)
            acc[a][b] = (intx4){0, 0, 0, 0};

    // 21 DMA instrs/chunk over 8 waves: wave W issues i = W, W+8, W+16 (<21)
    auto stage = [&](const unsigned char* ga, const unsigned char* gb, l_u8* ldsb) {
        #pragma unroll
        for (int u = 0; u < 3; ++u) {
            if (W + 8 * u < 21) {
                int i = W + 8 * u;
                const unsigned char* g = (i < 14) ? ga + (i * 64 + lane) * 16
                                                  : gb + ((i - 14) * 64 + lane) * 16;
                __builtin_amdgcn_global_load_lds((const g_u8*)g, ldsb + i * 1024, 16, 0, 0);
            }
        }
    };

    stage(gA, gB, lds0);         gA += CHB;  gB += CHB;   // chunk 0 -> buf0
    stage(gA, gB, lds0 + BUFB);  gA += CHB;  gB += CHB;   // chunk 1 -> buf1

    for (int cb = 0; cb < NCH; cb += 3) {
        #pragma unroll
        for (int cc = 0; cc < 3; ++cc) {
            int c = cb + cc;
            // counted wait: drain own chunk-c DMAs, keep chunk c+1's in
            // flight across the barrier (proven-safe R13/R14 skeleton).
            if (c == NCH - 1) __builtin_amdgcn_s_waitcnt(0xF70);       // vmcnt(0)
            else              __builtin_amdgcn_s_waitcnt(0xF70 | VM);  // vmcnt(VM)
            __builtin_amdgcn_s_barrier();
            __builtin_amdgcn_sched_barrier(0);   // pin: no ds_read above barrier

            intx4 afr[AC], bfr[BC];
            #pragma unroll
            for (int a = 0; a < AC; ++a)
                afr[a] = *(const intx4*)(abp + cc * BUFB + (AS + a) * 1024);
            #pragma unroll
            for (int b = 0; b < BC; ++b)
                bfr[b] = *(const intx4*)(bbp + cc * BUFB + (BS + b) * 1024);

            if (c + 2 < NCH) {                   // stage chunk c+2 -> buf[(c+2)%3]
                stage(gA, gB, lds0 + ((cc + 2) % 3) * BUFB);
                gA += CHB;  gB += CHB;
            }

            __builtin_amdgcn_s_setprio(1);
            #pragma unroll
            for (int a = 0; a < AC; ++a)
                #pragma unroll
                for (int b = 0; b < BC; ++b)
                    acc[a][b] = __builtin_amdgcn_mfma_i32_16x16x64_i8(
                        afr[a], bfr[b], acc[a][b], 0, 0, 0);
            __builtin_amdgcn_s_setprio(0);
        }
    }

    __syncthreads();                 // all waves' tile reads done; alias LDS
    float* colmaxrow = (float*)tiles + W * 112;

    // C/D: col q = lane&15, row p = (AS+a)*16 + quad*4 + r (shape-determined
    // layout, dtype-independent). Max in exact i32, convert once at the end.
    #pragma unroll
    for (int b = 0; b < BC; ++b) {
        int m = (int)0x80000000;
        #pragma unroll
        for (int a = 0; a < AC; ++a) {
            int pbase = (AS + a) * 16 + quad * 4;
            #pragma unroll
            for (int r = 0; r < 4; ++r)
                if (pbase + r < P) m = max(m, acc[a][b][r]);
        }
        m = max(m, __shfl_xor(m, 16));
        m = max(m, __shfl_xor(m, 32));
        if (quad == 0) colmaxrow[(BS + b) * 16 + r16] = (float)m * INV_QS2;
    }
    // non-owned columns of this wave's row: neutral element (final reduce
    // maxes over all 8 rows; stale LDS there would alias tile data)
    #pragma unroll
    for (int t = 0; t < 7; ++t)
        if (t < BS || t >= BS + BC)
            if (quad == 0) colmaxrow[t * 16 + r16] = -3.0e38f;
}

__global__ __launch_bounds__(512, 4) void pair_kernel(const unsigned char* __restrict__ Y,
                                                      float* __restrict__ out) {
    __shared__ uint4 tiles[3 * TPB];   // 64512 B (colmax aliased in epilogue)
    __shared__ float redp[8];

    int bx = blockIdx.x;
    int l  = (bx & 7) * 380 + (bx >> 3);   // XCD k owns logical [380k, 380k+380)
    int b  = l >> 1;                 // pair index (macro-tiled order)
    int qh = l & 1;                  // q-half
    unsigned short pk = PTAB.v[b];
    int ia = pk & 255;
    int ja = pk >> 8;
    bool is_nn = b < 496;

    int tid  = threadIdx.x;
    int lane = tid & 63;
    int wave = tid >> 6;             // 0..7

    const unsigned char* gA = Y + (size_t)ia * (NCH * CHB);
    const unsigned char* gB = Y + (size_t)ja * (NCH * CHB) + qh * (BPIECES * 16);

    switch (wave) {
        case 0: wave_worker<0>(tiles, gA, gB, lane); break;
        case 1: wave_worker<1>(tiles, gA, gB, lane); break;
        case 2: wave_worker<2>(tiles, gA, gB, lane); break;
        case 3: wave_worker<3>(tiles, gA, gB, lane); break;
        case 4: wave_worker<4>(tiles, gA, gB, lane); break;
        case 5: wave_worker<5>(tiles, gA, gB, lane); break;
        case 6: wave_worker<6>(tiles, gA, gB, lane); break;
        default: wave_worker<7>(tiles, gA, gB, lane); break;
    }

    __syncthreads();                 // all colmax rows written
    float* colmax = (float*)tiles;   // [8][112]

    float contrib = 0.f;
    if (tid < 112 && qh * 112 + tid < P) {       // q >= 196 are pad cols
        float cm = colmax[tid];
        #pragma unroll
        for (int w = 1; w < 8; ++w) cm = fmaxf(cm, colmax[w * 112 + tid]);
        contrib = is_nn ? (1.0f - cm) * (1.0f / (496.0f * 196.0f))
                        : fmaxf(cm - MARGIN, 0.0f) * (1.0f / (1024.0f * 196.0f));
    }
    #pragma unroll
    for (int o = 32; o > 0; o >>= 1) contrib += __shfl_down(contrib, o);
    if (lane == 0) redp[wave] = contrib;
    __syncthreads();
    if (tid == 0) {
        float s = redp[0] + redp[1] + redp[2] + redp[3]
                + redp[4] + redp[5] + redp[6] + redp[7];
        atomicAdd(out, s);
    }
}

// ---------------------------------------------------------------------------
extern "C" void kernel_launch(void* const* d_in, const int* in_sizes, int n_in,
                              void* d_out, int out_size, void* d_ws, size_t ws_size,
                              hipStream_t stream) {
    const float* nrm = (const float*)d_in[0];   // [32,196,768] fp32
    const float* dft = (const float*)d_in[1];   // [32,196,768] fp32
    float* out = (float*)d_out;                 // scalar fp32
    unsigned char* Y = (unsigned char*)d_ws;    // int8, 10.5 MB

    norm_kernel<<<64 * 28, 512, 0, stream>>>(nrm, dft, Y, out);
    pair_kernel<<<2 * (496 + 1024), 512, 0, stream>>>(Y, out);
}